// Round 1
// baseline (265.429 us; speedup 1.0000x reference)
//
#include <hip/hip_runtime.h>
#include <math.h>

#define NHOP 2
#define MEM 32
#define DIM 64

__global__ __launch_bounds__(256) void ripple_fwd(
    const float* __restrict__ hs,     // (B,2,32,64)
    const float* __restrict__ Rs,     // (B,2,32,64,64)
    const float* __restrict__ ts,     // (B,2,32,64)
    const float* __restrict__ vs,     // (B,64)
    const float* __restrict__ W1_w,   // (64,256)
    const float* __restrict__ W1_b,   // (64)
    const float* __restrict__ W2_w,   // (1,64)
    const float* __restrict__ W2_b,   // (1)
    const float* __restrict__ Wmem_w, // (2,64,192)
    const float* __restrict__ Wmem_b, // (2,64)
    const float* __restrict__ z_w,    // (64,128)
    const float* __restrict__ z_b,    // (64)
    float* __restrict__ out)          // (B)
{
    __shared__ float W1T[256][64];        // W1 transposed: W1T[f][d], 64 KB
    __shared__ float Rh_sm[MEM][DIM + 1]; // +1 pad: breaks bank conflict on Rh_sm[mg][e]
    __shared__ float M_sm[DIM], o_sm[DIM], onew_sm[DIM], vs_sm[DIM];
    __shared__ float Z_sm[MEM], g_sm[MEM];

    const int b   = blockIdx.x;
    const int tid = threadIdx.x;

    // Stage W1 transposed into LDS (one-time; write conflicts tolerated).
    #pragma unroll 8
    for (int k = 0; k < 64; ++k)
        W1T[tid][k] = W1_w[k * 256 + tid];   // global read coalesced over tid=f

    if (tid < DIM) {
        const float v = vs[b * DIM + tid];
        M_sm[tid] = v; o_sm[tid] = v; vs_sm[tid] = v;
    }
    __syncthreads();

    for (int hop = 0; hop < NHOP; ++hop) {
        const float* __restrict__ hbase = hs + (size_t)(b * NHOP + hop) * MEM * DIM;
        const float* __restrict__ Rbase = Rs + (size_t)(b * NHOP + hop) * MEM * DIM * DIM;
        const float* __restrict__ tbase = ts + (size_t)(b * NHOP + hop) * MEM * DIM;

        // ---- Phase 1: Rh[m][d] = sum_e R[m,d,e] * h[m,e]  (the 1 GiB stream) ----
        {
            const int d  = tid & 63;
            const int wv = tid >> 6;           // wave id 0..3 -> m is wave-uniform
            for (int k = 0; k < 8; ++k) {
                const int m = k * 4 + wv;
                const float* __restrict__ Rrow = Rbase + (size_t)(m * DIM + d) * DIM;
                const float* __restrict__ hrow = hbase + m * DIM;
                float acc = 0.f;
                #pragma unroll
                for (int e4 = 0; e4 < 16; ++e4) {
                    const float4 r  = *reinterpret_cast<const float4*>(Rrow + 4 * e4);
                    const float4 hh = *reinterpret_cast<const float4*>(hrow + 4 * e4);
                    acc += r.x * hh.x + r.y * hh.y + r.z * hh.z + r.w * hh.w;
                }
                Rh_sm[m][d] = acc;
            }
        }
        __syncthreads();

        // ---- Phase 2: hcode = tanh(W1 @ z + b1); Z[m] = W2 . hcode + b2 ----
        // Thread layout: d4 = tid&15 covers d = 4*d4..4*d4+3 ; mg = tid>>4 covers m = mg, mg+16
        {
            const int d4 = tid & 15;
            const int mg = tid >> 4;
            float acc0[4] = {0.f, 0.f, 0.f, 0.f};
            float acc1[4] = {0.f, 0.f, 0.f, 0.f};
            #pragma unroll 4
            for (int e = 0; e < 64; ++e) {
                const float4 w0 = *reinterpret_cast<const float4*>(&W1T[e      ][d4 * 4]);
                const float4 w1 = *reinterpret_cast<const float4*>(&W1T[64  + e][d4 * 4]);
                const float4 w2 = *reinterpret_cast<const float4*>(&W1T[128 + e][d4 * 4]);
                const float4 w3 = *reinterpret_cast<const float4*>(&W1T[192 + e][d4 * 4]);
                const float oe  = o_sm[e];
                const float Me  = M_sm[e];
                const float rh0 = Rh_sm[mg][e];
                const float rh1 = Rh_sm[mg + 16][e];
                {
                    const float z0 = rh0 * oe, z1 = rh0 * Me;
                    const float z2 = fabsf(rh0 - oe), z3 = fabsf(rh0 - Me);
                    acc0[0] = fmaf(z0, w0.x, fmaf(z1, w1.x, fmaf(z2, w2.x, fmaf(z3, w3.x, acc0[0]))));
                    acc0[1] = fmaf(z0, w0.y, fmaf(z1, w1.y, fmaf(z2, w2.y, fmaf(z3, w3.y, acc0[1]))));
                    acc0[2] = fmaf(z0, w0.z, fmaf(z1, w1.z, fmaf(z2, w2.z, fmaf(z3, w3.z, acc0[2]))));
                    acc0[3] = fmaf(z0, w0.w, fmaf(z1, w1.w, fmaf(z2, w2.w, fmaf(z3, w3.w, acc0[3]))));
                }
                {
                    const float z0 = rh1 * oe, z1 = rh1 * Me;
                    const float z2 = fabsf(rh1 - oe), z3 = fabsf(rh1 - Me);
                    acc1[0] = fmaf(z0, w0.x, fmaf(z1, w1.x, fmaf(z2, w2.x, fmaf(z3, w3.x, acc1[0]))));
                    acc1[1] = fmaf(z0, w0.y, fmaf(z1, w1.y, fmaf(z2, w2.y, fmaf(z3, w3.y, acc1[1]))));
                    acc1[2] = fmaf(z0, w0.z, fmaf(z1, w1.z, fmaf(z2, w2.z, fmaf(z3, w3.z, acc1[2]))));
                    acc1[3] = fmaf(z0, w0.w, fmaf(z1, w1.w, fmaf(z2, w2.w, fmaf(z3, w3.w, acc1[3]))));
                }
            }
            float p0 = 0.f, p1 = 0.f;
            #pragma unroll
            for (int k2 = 0; k2 < 4; ++k2) {
                const int dd = d4 * 4 + k2;
                const float w2v = W2_w[dd];
                p0 += tanhf(acc0[k2] + W1_b[dd]) * w2v;
                p1 += tanhf(acc1[k2] + W1_b[dd]) * w2v;
            }
            #pragma unroll
            for (int s = 1; s < 16; s <<= 1) {
                p0 += __shfl_xor(p0, s, 64);
                p1 += __shfl_xor(p1, s, 64);
            }
            if (d4 == 0) {
                Z_sm[mg]      = p0 + W2_b[0];
                Z_sm[mg + 16] = p1 + W2_b[0];
            }
        }
        __syncthreads();

        // ---- Phase 3: softmax over m ----
        if (tid < MEM) {
            float mx = Z_sm[0];
            #pragma unroll
            for (int m = 1; m < MEM; ++m) mx = fmaxf(mx, Z_sm[m]);
            float s = 0.f;
            #pragma unroll
            for (int m = 0; m < MEM; ++m) s += __expf(Z_sm[m] - mx);
            g_sm[tid] = __expf(Z_sm[tid] - mx) / s;
        }
        __syncthreads();

        // ---- Phase 4: o_new[d] = sum_m t[m,d] * g[m] ----
        if (tid < DIM) {
            float acc = 0.f;
            #pragma unroll 8
            for (int m = 0; m < MEM; ++m)
                acc += tbase[m * DIM + tid] * g_sm[m];
            onew_sm[tid] = acc;
        }
        __syncthreads();

        // ---- Phase 5: M = relu(Wmem[hop] @ [M, o_new, o] + b) ; o = o_new ----
        float Mn = 0.f;
        if (tid < DIM) {
            const float* __restrict__ Wm = Wmem_w + (size_t)(hop * DIM + tid) * 192;
            float acc = Wmem_b[hop * DIM + tid];
            #pragma unroll
            for (int k = 0; k < 16; ++k) {
                const float4 w = *reinterpret_cast<const float4*>(Wm + 4 * k);
                acc += w.x * M_sm[4*k] + w.y * M_sm[4*k+1] + w.z * M_sm[4*k+2] + w.w * M_sm[4*k+3];
            }
            #pragma unroll
            for (int k = 0; k < 16; ++k) {
                const float4 w = *reinterpret_cast<const float4*>(Wm + 64 + 4 * k);
                acc += w.x * onew_sm[4*k] + w.y * onew_sm[4*k+1] + w.z * onew_sm[4*k+2] + w.w * onew_sm[4*k+3];
            }
            #pragma unroll
            for (int k = 0; k < 16; ++k) {
                const float4 w = *reinterpret_cast<const float4*>(Wm + 128 + 4 * k);
                acc += w.x * o_sm[4*k] + w.y * o_sm[4*k+1] + w.z * o_sm[4*k+2] + w.w * o_sm[4*k+3];
            }
            Mn = fmaxf(acc, 0.f);
        }
        __syncthreads();   // everyone done reading old M_sm/o_sm
        if (tid < DIM) {
            M_sm[tid] = Mn;
            o_sm[tid] = onew_sm[tid];
        }
        __syncthreads();
    }

    // ---- Final: u = z_w @ [M, vs] + z_b ; out[b] = sum_d vs[d] * u[d] ----
    if (tid < DIM) {
        const float* __restrict__ zr = z_w + (size_t)tid * 128;
        float u = z_b[tid];
        #pragma unroll
        for (int k = 0; k < 16; ++k) {
            const float4 w = *reinterpret_cast<const float4*>(zr + 4 * k);
            u += w.x * M_sm[4*k] + w.y * M_sm[4*k+1] + w.z * M_sm[4*k+2] + w.w * M_sm[4*k+3];
        }
        #pragma unroll
        for (int k = 0; k < 16; ++k) {
            const float4 w = *reinterpret_cast<const float4*>(zr + 64 + 4 * k);
            u += w.x * vs_sm[4*k] + w.y * vs_sm[4*k+1] + w.z * vs_sm[4*k+2] + w.w * vs_sm[4*k+3];
        }
        float r = vs_sm[tid] * u;
        #pragma unroll
        for (int s = 1; s < 64; s <<= 1) r += __shfl_xor(r, s, 64);
        if (tid == 0) out[b] = r;
    }
}

extern "C" void kernel_launch(void* const* d_in, const int* in_sizes, int n_in,
                              void* d_out, int out_size, void* d_ws, size_t ws_size,
                              hipStream_t stream)
{
    const float* hs     = (const float*)d_in[0];
    const float* Rs     = (const float*)d_in[1];
    const float* ts     = (const float*)d_in[2];
    const float* vs     = (const float*)d_in[3];
    const float* W1_w   = (const float*)d_in[4];
    const float* W1_b   = (const float*)d_in[5];
    const float* W2_w   = (const float*)d_in[6];
    const float* W2_b   = (const float*)d_in[7];
    const float* Wmem_w = (const float*)d_in[8];
    const float* Wmem_b = (const float*)d_in[9];
    const float* z_w    = (const float*)d_in[10];
    const float* z_b    = (const float*)d_in[11];
    float* out = (float*)d_out;

    const int B = out_size;  // 1024
    ripple_fwd<<<B, 256, 0, stream>>>(hs, Rs, ts, vs, W1_w, W1_b, W2_w, W2_b,
                                      Wmem_w, Wmem_b, z_w, z_b, out);
}

// Round 2
// 217.714 us; speedup vs baseline: 1.2192x; 1.2192x over previous
//
#include <hip/hip_runtime.h>
#include <math.h>

#define NHOP 2
#define MEM 32
#define DIM 64

__global__ __launch_bounds__(256) void ripple_fwd(
    const float* __restrict__ hs,     // (B,2,32,64)
    const float* __restrict__ Rs,     // (B,2,32,64,64)
    const float* __restrict__ ts,     // (B,2,32,64)
    const float* __restrict__ vs,     // (B,64)
    const float* __restrict__ W1_w,   // (64,256)
    const float* __restrict__ W1_b,   // (64)
    const float* __restrict__ W2_w,   // (1,64)
    const float* __restrict__ W2_b,   // (1)
    const float* __restrict__ Wmem_w, // (2,64,192)
    const float* __restrict__ Wmem_b, // (2,64)
    const float* __restrict__ z_w,    // (64,128)
    const float* __restrict__ z_b,    // (64)
    float* __restrict__ out)          // (B)
{
    __shared__ float W1T[256][64];        // W1 transposed: W1T[f][d], 64 KB
    __shared__ float Rh_sm[MEM][DIM + 1]; // +1 pad: breaks bank conflict on Rh_sm[mg][e]
    __shared__ float M_sm[DIM], o_sm[DIM], onew_sm[DIM], vs_sm[DIM];
    __shared__ float Z_sm[MEM], g_sm[MEM];

    const int b   = blockIdx.x;
    const int tid = threadIdx.x;

    // Stage W1 transposed into LDS (one-time).
    #pragma unroll 8
    for (int k = 0; k < 64; ++k)
        W1T[tid][k] = W1_w[k * 256 + tid];   // global read coalesced over tid=f

    if (tid < DIM) {
        const float v = vs[b * DIM + tid];
        M_sm[tid] = v; o_sm[tid] = v; vs_sm[tid] = v;
    }
    __syncthreads();

    for (int hop = 0; hop < NHOP; ++hop) {
        const float* __restrict__ hbase = hs + (size_t)(b * NHOP + hop) * MEM * DIM;
        const float* __restrict__ Rbase = Rs + (size_t)(b * NHOP + hop) * MEM * DIM * DIM;
        const float* __restrict__ tbase = ts + (size_t)(b * NHOP + hop) * MEM * DIM;

        // ---- Phase 1: Rh[m][d] = sum_e R[m,d,e] * h[m,e]  (the 1 GiB stream) ----
        // Line-exact mapping: per instruction, 16 segments of 64B (stride 256B);
        // every fetched line is fully consumed by 4 lanes in the SAME instruction.
        // Lane l: e-slice e0=l&3 (covers e = 4*e0+16s, s=0..3), d-slot dq=l>>2.
        {
            const int l  = tid & 63;
            const int wv = tid >> 6;          // wave id -> m is wave-uniform
            const int e0 = l & 3;
            const int dq = l >> 2;
            #pragma unroll 2
            for (int k = 0; k < 8; ++k) {
                const int m = k * 4 + wv;
                const float* __restrict__ Rm = Rbase + (size_t)m * DIM * DIM;
                const float* __restrict__ hm = hbase + m * DIM;
                const float4 hv0 = *reinterpret_cast<const float4*>(hm + 4 * e0);
                const float4 hv1 = *reinterpret_cast<const float4*>(hm + 4 * e0 + 16);
                const float4 hv2 = *reinterpret_cast<const float4*>(hm + 4 * e0 + 32);
                const float4 hv3 = *reinterpret_cast<const float4*>(hm + 4 * e0 + 48);
                #pragma unroll
                for (int dblk = 0; dblk < 4; ++dblk) {
                    const int d = dblk * 16 + dq;
                    const float* __restrict__ row = Rm + d * DIM + 4 * e0;
                    const float4 r0 = *reinterpret_cast<const float4*>(row);
                    const float4 r1 = *reinterpret_cast<const float4*>(row + 16);
                    const float4 r2 = *reinterpret_cast<const float4*>(row + 32);
                    const float4 r3 = *reinterpret_cast<const float4*>(row + 48);
                    float p = r0.x*hv0.x + r0.y*hv0.y + r0.z*hv0.z + r0.w*hv0.w;
                    p = fmaf(r1.x, hv1.x, fmaf(r1.y, hv1.y, fmaf(r1.z, hv1.z, fmaf(r1.w, hv1.w, p))));
                    p = fmaf(r2.x, hv2.x, fmaf(r2.y, hv2.y, fmaf(r2.z, hv2.z, fmaf(r2.w, hv2.w, p))));
                    p = fmaf(r3.x, hv3.x, fmaf(r3.y, hv3.y, fmaf(r3.z, hv3.z, fmaf(r3.w, hv3.w, p))));
                    // complete e-sum across the 4 lanes sharing d
                    p += __shfl_xor(p, 1);
                    p += __shfl_xor(p, 2);
                    if (e0 == 0) Rh_sm[m][d] = p;  // 16 lanes, consecutive d -> conflict-free
                }
            }
        }
        __syncthreads();

        // ---- Phase 2: hcode = tanh(W1 @ z + b1); Z[m] = W2 . hcode + b2 ----
        // Thread layout: d4 = tid&15 covers d = 4*d4..4*d4+3 ; mg = tid>>4 covers m = mg, mg+16
        {
            const int d4 = tid & 15;
            const int mg = tid >> 4;
            float acc0[4] = {0.f, 0.f, 0.f, 0.f};
            float acc1[4] = {0.f, 0.f, 0.f, 0.f};
            #pragma unroll 4
            for (int e = 0; e < 64; ++e) {
                const float4 w0 = *reinterpret_cast<const float4*>(&W1T[e      ][d4 * 4]);
                const float4 w1 = *reinterpret_cast<const float4*>(&W1T[64  + e][d4 * 4]);
                const float4 w2 = *reinterpret_cast<const float4*>(&W1T[128 + e][d4 * 4]);
                const float4 w3 = *reinterpret_cast<const float4*>(&W1T[192 + e][d4 * 4]);
                const float oe  = o_sm[e];
                const float Me  = M_sm[e];
                const float rh0 = Rh_sm[mg][e];
                const float rh1 = Rh_sm[mg + 16][e];
                {
                    const float z0 = rh0 * oe, z1 = rh0 * Me;
                    const float z2 = fabsf(rh0 - oe), z3 = fabsf(rh0 - Me);
                    acc0[0] = fmaf(z0, w0.x, fmaf(z1, w1.x, fmaf(z2, w2.x, fmaf(z3, w3.x, acc0[0]))));
                    acc0[1] = fmaf(z0, w0.y, fmaf(z1, w1.y, fmaf(z2, w2.y, fmaf(z3, w3.y, acc0[1]))));
                    acc0[2] = fmaf(z0, w0.z, fmaf(z1, w1.z, fmaf(z2, w2.z, fmaf(z3, w3.z, acc0[2]))));
                    acc0[3] = fmaf(z0, w0.w, fmaf(z1, w1.w, fmaf(z2, w2.w, fmaf(z3, w3.w, acc0[3]))));
                }
                {
                    const float z0 = rh1 * oe, z1 = rh1 * Me;
                    const float z2 = fabsf(rh1 - oe), z3 = fabsf(rh1 - Me);
                    acc1[0] = fmaf(z0, w0.x, fmaf(z1, w1.x, fmaf(z2, w2.x, fmaf(z3, w3.x, acc1[0]))));
                    acc1[1] = fmaf(z0, w0.y, fmaf(z1, w1.y, fmaf(z2, w2.y, fmaf(z3, w3.y, acc1[1]))));
                    acc1[2] = fmaf(z0, w0.z, fmaf(z1, w1.z, fmaf(z2, w2.z, fmaf(z3, w3.z, acc1[2]))));
                    acc1[3] = fmaf(z0, w0.w, fmaf(z1, w1.w, fmaf(z2, w2.w, fmaf(z3, w3.w, acc1[3]))));
                }
            }
            float p0 = 0.f, p1 = 0.f;
            #pragma unroll
            for (int k2 = 0; k2 < 4; ++k2) {
                const int dd = d4 * 4 + k2;
                const float w2v = W2_w[dd];
                p0 += tanhf(acc0[k2] + W1_b[dd]) * w2v;
                p1 += tanhf(acc1[k2] + W1_b[dd]) * w2v;
            }
            #pragma unroll
            for (int s = 1; s < 16; s <<= 1) {
                p0 += __shfl_xor(p0, s, 64);
                p1 += __shfl_xor(p1, s, 64);
            }
            if (d4 == 0) {
                Z_sm[mg]      = p0 + W2_b[0];
                Z_sm[mg + 16] = p1 + W2_b[0];
            }
        }
        __syncthreads();

        // ---- Phase 3: softmax over m ----
        if (tid < MEM) {
            float mx = Z_sm[0];
            #pragma unroll
            for (int m = 1; m < MEM; ++m) mx = fmaxf(mx, Z_sm[m]);
            float s = 0.f;
            #pragma unroll
            for (int m = 0; m < MEM; ++m) s += __expf(Z_sm[m] - mx);
            g_sm[tid] = __expf(Z_sm[tid] - mx) / s;
        }
        __syncthreads();

        // ---- Phase 4: o_new[d] = sum_m t[m,d] * g[m] ----
        if (tid < DIM) {
            float acc = 0.f;
            #pragma unroll 8
            for (int m = 0; m < MEM; ++m)
                acc += tbase[m * DIM + tid] * g_sm[m];
            onew_sm[tid] = acc;
        }
        __syncthreads();

        // ---- Phase 5: M = relu(Wmem[hop] @ [M, o_new, o] + b) ; o = o_new ----
        float Mn = 0.f;
        if (tid < DIM) {
            const float* __restrict__ Wm = Wmem_w + (size_t)(hop * DIM + tid) * 192;
            float acc = Wmem_b[hop * DIM + tid];
            #pragma unroll
            for (int k = 0; k < 16; ++k) {
                const float4 w = *reinterpret_cast<const float4*>(Wm + 4 * k);
                acc += w.x * M_sm[4*k] + w.y * M_sm[4*k+1] + w.z * M_sm[4*k+2] + w.w * M_sm[4*k+3];
            }
            #pragma unroll
            for (int k = 0; k < 16; ++k) {
                const float4 w = *reinterpret_cast<const float4*>(Wm + 64 + 4 * k);
                acc += w.x * onew_sm[4*k] + w.y * onew_sm[4*k+1] + w.z * onew_sm[4*k+2] + w.w * onew_sm[4*k+3];
            }
            #pragma unroll
            for (int k = 0; k < 16; ++k) {
                const float4 w = *reinterpret_cast<const float4*>(Wm + 128 + 4 * k);
                acc += w.x * o_sm[4*k] + w.y * o_sm[4*k+1] + w.z * o_sm[4*k+2] + w.w * o_sm[4*k+3];
            }
            Mn = fmaxf(acc, 0.f);
        }
        __syncthreads();   // everyone done reading old M_sm/o_sm
        if (tid < DIM) {
            M_sm[tid] = Mn;
            o_sm[tid] = onew_sm[tid];
        }
        __syncthreads();
    }

    // ---- Final: u = z_w @ [M, vs] + z_b ; out[b] = sum_d vs[d] * u[d] ----
    if (tid < DIM) {
        const float* __restrict__ zr = z_w + (size_t)tid * 128;
        float u = z_b[tid];
        #pragma unroll
        for (int k = 0; k < 16; ++k) {
            const float4 w = *reinterpret_cast<const float4*>(zr + 4 * k);
            u += w.x * M_sm[4*k] + w.y * M_sm[4*k+1] + w.z * M_sm[4*k+2] + w.w * M_sm[4*k+3];
        }
        #pragma unroll
        for (int k = 0; k < 16; ++k) {
            const float4 w = *reinterpret_cast<const float4*>(zr + 64 + 4 * k);
            u += w.x * vs_sm[4*k] + w.y * vs_sm[4*k+1] + w.z * vs_sm[4*k+2] + w.w * vs_sm[4*k+3];
        }
        float r = vs_sm[tid] * u;
        #pragma unroll
        for (int s = 1; s < 64; s <<= 1) r += __shfl_xor(r, s, 64);
        if (tid == 0) out[b] = r;
    }
}

extern "C" void kernel_launch(void* const* d_in, const int* in_sizes, int n_in,
                              void* d_out, int out_size, void* d_ws, size_t ws_size,
                              hipStream_t stream)
{
    const float* hs     = (const float*)d_in[0];
    const float* Rs     = (const float*)d_in[1];
    const float* ts     = (const float*)d_in[2];
    const float* vs     = (const float*)d_in[3];
    const float* W1_w   = (const float*)d_in[4];
    const float* W1_b   = (const float*)d_in[5];
    const float* W2_w   = (const float*)d_in[6];
    const float* W2_b   = (const float*)d_in[7];
    const float* Wmem_w = (const float*)d_in[8];
    const float* Wmem_b = (const float*)d_in[9];
    const float* z_w    = (const float*)d_in[10];
    const float* z_b    = (const float*)d_in[11];
    float* out = (float*)d_out;

    const int B = out_size;  // 1024
    ripple_fwd<<<B, 256, 0, stream>>>(hs, Rs, ts, vs, W1_w, W1_b, W2_w, W2_b,
                                      Wmem_w, Wmem_b, z_w, z_b, out);
}